// Round 9
// baseline (325.006 us; speedup 1.0000x reference)
//
#include <hip/hip_runtime.h>

// Problem constants (B=1)
#define SS 2048
#define DD 2048
#define HH 16
#define DHD 128

// scores scale: reference divides by sqrt(DH) with DH=128
#define SCORE_SCALE 0.08838834764831845f
// p = exp(50*tanh(u)-50) with u = s*SCORE_SCALE/50  ==>  p = exp(-100/(1+e^{2u}))
#define C2 0.0035355339059327377f

typedef unsigned short u16;
typedef __attribute__((ext_vector_type(8))) short short8;
typedef __attribute__((ext_vector_type(4))) short short4v;
typedef __attribute__((ext_vector_type(4))) float f32x4;

__device__ __forceinline__ float bf2f(u16 v) {
  union { unsigned u; float f; } x; x.u = ((unsigned)v) << 16; return x.f;
}
__device__ __forceinline__ u16 f2bf(float f) {
  union { float f; unsigned u; } x; x.f = f;
  unsigned r = (x.u + 0x7fffu + ((x.u >> 16) & 1u)) >> 16;  // RTNE
  return (u16)r;
}

// async global->LDS, 16B per lane; LDS dest = wave-uniform base + lane*16
#define GL2LDS16(g, l) __builtin_amdgcn_global_load_lds( \
    (const __attribute__((address_space(1))) void*)(g),   \
    (__attribute__((address_space(3))) void*)(l), 16, 0, 0)

// ---------------- batched f32 -> bf16 convert (5 tensors in one launch) ------
__global__ __launch_bounds__(256) void cvt5(const float* __restrict__ i0,
                                            const float* __restrict__ i1,
                                            const float* __restrict__ i2,
                                            const float* __restrict__ i3,
                                            const float* __restrict__ i4,
                                            u16* __restrict__ o0, u16* __restrict__ o1,
                                            u16* __restrict__ o2, u16* __restrict__ o3,
                                            u16* __restrict__ o4) {
  const int z = blockIdx.y;
  const float* in = (z == 0) ? i0 : (z == 1) ? i1 : (z == 2) ? i2 : (z == 3) ? i3 : i4;
  u16* out = (z == 0) ? o0 : (z == 1) ? o1 : (z == 2) ? o2 : (z == 3) ? o3 : o4;
  int i = (blockIdx.x * 256 + threadIdx.x) * 8;
  float4 a = *(const float4*)(in + i);
  float4 b = *(const float4*)(in + i + 4);
  short8 o;
  o[0] = (short)f2bf(a.x); o[1] = (short)f2bf(a.y);
  o[2] = (short)f2bf(a.z); o[3] = (short)f2bf(a.w);
  o[4] = (short)f2bf(b.x); o[5] = (short)f2bf(b.y);
  o[6] = (short)f2bf(b.z); o[7] = (short)f2bf(b.w);
  *(short8*)(out + i) = o;
}

// ============ shared GEMM K-loop pieces (128x128 tile, BK=32, 2-phase) =======
// LDS swizzle: element (row, 8-elem chunk c) stored at slot c ^ ((row>>1)&3).
// Rows 0..7 then cover 8 distinct 16B segments = all 32 banks; rows 8..15
// repeat -> 2 lanes/bank = free (m136). Staging keeps LDS dest LINEAR
// (gl2lds req) and pre-swizzles the GLOBAL source chunk (m173 pattern);
// within each 4-lane group chunks are a permutation of one 64B segment,
// so global coalescing is preserved.

#define GEMM_STAGE(Asrc, Bsrc, Adst, Bdst, kofs)                               \
  _Pragma("unroll")                                                            \
  for (int half = 0; half < 2; ++half) {                                       \
    const int rb = half * 64 + wave * 16;                                      \
    GL2LDS16(Asrc + (size_t)(bm + rb + lrow) * DD + (kofs) + c8s, Adst + rb * 32); \
    GL2LDS16(Bsrc + (size_t)(bn + rb + lrow) * DD + (kofs) + c8s, Bdst + rb * 32); \
  }

#define GEMM_COMPUTE(Abuf, Bbuf)                                               \
  {                                                                            \
    short8 af[4], bb[4];                                                       \
    _Pragma("unroll")                                                          \
    for (int m = 0; m < 4; ++m) {                                              \
      const int row = wm + m * 16 + fr;                                        \
      af[m] = *(const short8*)(Abuf + row * 32 + (hi ^ ((row >> 1) & 3)) * 8); \
    }                                                                          \
    _Pragma("unroll")                                                          \
    for (int n = 0; n < 4; ++n) {                                              \
      const int row = wn + n * 16 + fr;                                        \
      bb[n] = *(const short8*)(Bbuf + row * 32 + (hi ^ ((row >> 1) & 3)) * 8); \
    }                                                                          \
    __builtin_amdgcn_s_setprio(1);                                             \
    _Pragma("unroll")                                                          \
    for (int m = 0; m < 4; ++m)                                                \
      _Pragma("unroll")                                                        \
      for (int n = 0; n < 4; ++n)                                              \
        acc[m][n] = __builtin_amdgcn_mfma_f32_16x16x32_bf16(af[m], bb[n], acc[m][n], 0, 0, 0); \
    __builtin_amdgcn_s_setprio(0);                                             \
  }

// 2-phase double-buffered K-loop over DD, named buffers (rule #20)
#define GEMM_KLOOP(A_, B_)                                                     \
  GEMM_STAGE(A_, B_, As0, Bs0, 0)                                              \
  __syncthreads();                                                             \
  for (int kk = 0; kk < DD / 32; kk += 2) {                                    \
    if (kk + 1 < DD / 32) { GEMM_STAGE(A_, B_, As1, Bs1, (kk + 1) * 32) }      \
    GEMM_COMPUTE(As0, Bs0)                                                     \
    __syncthreads();                                                           \
    if (kk + 2 < DD / 32) { GEMM_STAGE(A_, B_, As0, Bs0, (kk + 2) * 32) }      \
    GEMM_COMPUTE(As1, Bs1)                                                     \
    __syncthreads();                                                           \
  }

// ---------------- out-proj GEMM: C[M][N] = A[M][K] * B[N][K]^T, f32 out ------
__global__ __launch_bounds__(256) void gemm_bt(const u16* __restrict__ A,
                                               const u16* __restrict__ B,
                                               float* __restrict__ C) {
  __shared__ u16 smem[16384];  // As0|As1|Bs0|Bs1 (4KB elems each)
  u16* As0 = smem;            u16* As1 = smem + 4096;
  u16* Bs0 = smem + 8192;     u16* Bs1 = smem + 12288;
  const int tid = threadIdx.x, wave = tid >> 6, lane = tid & 63;
  const int wm = (wave >> 1) * 64, wn = (wave & 1) * 64;
  const int bm = blockIdx.y * 128, bn = blockIdx.x * 128;
  const int lrow = lane >> 2;
  const int c8s = ((lane & 3) ^ ((lrow >> 1) & 3)) * 8;  // pre-swizzled src chunk
  const int fr = lane & 15, hi = lane >> 4, fq4 = hi * 4;
  f32x4 acc[4][4] = {};
  GEMM_KLOOP(A, B)
#pragma unroll
  for (int m = 0; m < 4; ++m)
#pragma unroll
    for (int n = 0; n < 4; ++n) {
      const int row0 = bm + wm + m * 16 + fq4;
      const int col  = bn + wn + n * 16 + fr;
#pragma unroll
      for (int r = 0; r < 4; ++r)
        C[(size_t)(row0 + r) * DD + col] = acc[m][n][r];
    }
}

// ------- QKV GEMM with fused RoPE epilogue (z=0:Q->qt, 1:K->kt, 2:V->vt) ----
// One bn block = one head (128 cols). For z<2 the epilogue stores the C tile
// to LDS (bf16, [128][136] padded), then applies RoPE (pairs d <-> d^64) and
// writes [H][S][DH] directly. Kills the separate rope kernel + intermediates.
__global__ __launch_bounds__(256) void gemm_qkv(const u16* __restrict__ A,
                                                const u16* __restrict__ Bq,
                                                const u16* __restrict__ Bk,
                                                const u16* __restrict__ Bv,
                                                const float* __restrict__ cosd,
                                                const float* __restrict__ sind,
                                                u16* __restrict__ qt,
                                                u16* __restrict__ kt,
                                                u16* __restrict__ vt) {
  __shared__ u16 smem[18432];  // 36KB: staging (32KB) unioned with Ct (34.8KB)
  u16* As0 = smem;            u16* As1 = smem + 4096;
  u16* Bs0 = smem + 8192;     u16* Bs1 = smem + 12288;
  const int z = blockIdx.z;
  const u16* B = (z == 0) ? Bq : (z == 1) ? Bk : Bv;
  const int tid = threadIdx.x, wave = tid >> 6, lane = tid & 63;
  const int wm = (wave >> 1) * 64, wn = (wave & 1) * 64;
  const int bm = blockIdx.y * 128, bn = blockIdx.x * 128;
  const int lrow = lane >> 2;
  const int c8s = ((lane & 3) ^ ((lrow >> 1) & 3)) * 8;
  const int fr = lane & 15, hi = lane >> 4, fq4 = hi * 4;
  f32x4 acc[4][4] = {};
  GEMM_KLOOP(A, B)

  if (z == 2) {  // V: store transposed [H*DH][S] for attn's V^T staging
#pragma unroll
    for (int m = 0; m < 4; ++m)
#pragma unroll
      for (int n = 0; n < 4; ++n) {
        const int row0 = bm + wm + m * 16 + fq4;
        const int col  = bn + wn + n * 16 + fr;
        short4v t;
#pragma unroll
        for (int r = 0; r < 4; ++r) t[r] = (short)f2bf(acc[m][n][r]);
        *(short4v*)(vt + (size_t)col * SS + row0) = t;
      }
    return;
  }

  // ---- fused RoPE epilogue (z<2) ----
  u16* Ct = smem;  // [128][136] bf16 (pad 8: rows advance 4 banks -> ~2-way)
#pragma unroll
  for (int m = 0; m < 4; ++m)
#pragma unroll
    for (int n = 0; n < 4; ++n) {
      const int rrow = wm + m * 16 + fq4;
      const int col  = wn + n * 16 + fr;
#pragma unroll
      for (int r = 0; r < 4; ++r)
        Ct[(rrow + r) * 136 + col] = f2bf(acc[m][n][r]);
    }
  __syncthreads();

  const int row  = tid >> 1;          // 0..127 local s
  const int half = tid & 1;           // 0: d 0..63, 1: d 64..127
  const int d0   = half * 64;
  const int srow = bm + row;
  const int head = blockIdx.x;        // 128 cols == one head
  const float sgn = half ? 1.0f : -1.0f;  // rotate_half sign
  u16* dst = (z == 0) ? qt : kt;
#pragma unroll
  for (int j = 0; j < 8; ++j) {
    const int d = d0 + j * 8;
    f32x4 c0 = *(const f32x4*)(cosd + (size_t)srow * DHD + d);
    f32x4 c1 = *(const f32x4*)(cosd + (size_t)srow * DHD + d + 4);
    f32x4 s0 = *(const f32x4*)(sind + (size_t)srow * DHD + d);
    f32x4 s1 = *(const f32x4*)(sind + (size_t)srow * DHD + d + 4);
    short8 xo = *(const short8*)(Ct + row * 136 + d);
    short8 xp = *(const short8*)(Ct + row * 136 + (d ^ 64));
    short8 o;
#pragma unroll
    for (int jj = 0; jj < 8; ++jj) {
      const float c = (jj < 4) ? c0[jj] : c1[jj - 4];
      const float s = (jj < 4) ? s0[jj] : s1[jj - 4];
      o[jj] = (short)f2bf(bf2f((u16)xo[jj]) * c + sgn * bf2f((u16)xp[jj]) * s);
    }
    *(short8*)(dst + ((size_t)head * SS + srow) * DHD + d) = o;
  }
}

// ---------------- Flash attention (causal, tanh soft-cap 50) -----------------
// 1-D grid 512 blocks. h = (bid&7)+8*((bid>>3)&1): each XCD keeps 2 heads' K/V
// in its L2. qb = 31-(bid>>4): LPT schedule. FIXED-max softmax (cap -> m=50):
//   p = exp(s-50) = exp(-100/(1+e^{2u})) -- no online max/rescale.
__global__ __launch_bounds__(256) void attn_fwd(const u16* __restrict__ qt,
                                                const u16* __restrict__ kt,
                                                const u16* __restrict__ vt,
                                                u16* __restrict__ ao) {
  __shared__ u16 Ks[2][64 * 128];
  __shared__ u16 Vs[2][128 * 64];
  __shared__ u16 Ps[4][16 * 64];
  const int bid = blockIdx.x;
  const int h  = (bid & 7) + 8 * ((bid >> 3) & 1);
  const int qb = (SS / 64 - 1) - (bid >> 4);
  const int tid = threadIdx.x, wave = tid >> 6, lane = tid & 63;
  const int q0 = qb * 64 + wave * 16;
  const int fr = lane & 15, hi = lane >> 4, fq8 = hi * 8, fq4 = hi * 4;

  const int kbrow0 = wave * 4 + (lane >> 4);
  const int kc8    = (lane & 15);
  const int vbrow0 = wave * 8 + (lane >> 3);
  const int vk8    = (lane & 7) ^ ((lane >> 3) & 7);

  short8 qf[4];
#pragma unroll
  for (int c = 0; c < 4; ++c)
    qf[c] = *(const short8*)(qt + ((size_t)h * SS + q0 + fr) * DHD + c * 32 + fq8);

  f32x4 oacc[8] = {};
  float lsum[4] = {0.f, 0.f, 0.f, 0.f};

  const int nt = qb + 1;

  auto STAGE = [&](int t, int buf) {
    const int kb = t * 64;
#pragma unroll
    for (int i = 0; i < 4; ++i) {
      const int krow = i * 16 + kbrow0;
      const int c8 = kc8 ^ (krow & 7);
      GL2LDS16(kt + ((size_t)h * SS + kb + krow) * DHD + c8 * 8,
               &Ks[buf][(i * 16 + wave * 4) * 128]);
    }
#pragma unroll
    for (int i = 0; i < 4; ++i) {
      const int vrow = i * 32 + vbrow0;
      GL2LDS16(vt + ((size_t)h * DHD + vrow) * SS + kb + vk8 * 8,
               &Vs[buf][(i * 32 + wave * 8) * 64]);
    }
  };

  STAGE(0, 0);
  __syncthreads();

  for (int t = 0; t < nt; ++t) {
    const int buf = t & 1;
    if (t + 1 < nt) STAGE(t + 1, buf ^ 1);
    const int kb = t * 64;

    // S = Q K^T  (swizzled K reads)
    f32x4 sacc[4] = {};
    __builtin_amdgcn_s_setprio(1);
#pragma unroll
    for (int n = 0; n < 4; ++n) {
      const int row = n * 16 + fr;
#pragma unroll
      for (int c = 0; c < 4; ++c) {
        short8 b = *(const short8*)(&Ks[buf][row * 128 + ((c * 4 + hi) ^ (fr & 7)) * 8]);
        sacc[n] = __builtin_amdgcn_mfma_f32_16x16x32_bf16(qf[c], b, sacc[n], 0, 0, 0);
      }
    }
    __builtin_amdgcn_s_setprio(0);

    // fixed-max softcap softmax: p = exp(-100/(1+e^{2u})), masked -> 0
    const bool diag = (t == nt - 1);
    float p[4][4];
#pragma unroll
    for (int n = 0; n < 4; ++n)
#pragma unroll
      for (int r = 0; r < 4; ++r) {
        const float w = __expf(sacc[n][r] * C2);
        float pv = __expf(-100.0f * __builtin_amdgcn_rcpf(1.0f + w));
        if (diag) {
          const int kg = kb + n * 16 + fr;
          if (kg > q0 + fq4 + r) pv = 0.0f;
        }
        p[n][r] = pv;
        lsum[r] += pv;
      }

    // P (C-layout) -> per-wave LDS (swizzled) -> A-fragment layout
    u16* ps = &Ps[wave][0];
#pragma unroll
    for (int n = 0; n < 4; ++n)
#pragma unroll
      for (int r = 0; r < 4; ++r) {
        const int prow = fq4 + r;
        const int chunk = n * 2 + (fr >> 3);
        ps[prow * 64 + ((chunk ^ (prow & 7)) << 3) + (fr & 7)] = f2bf(p[n][r]);
      }
    short8 pa[2];
#pragma unroll
    for (int kc = 0; kc < 2; ++kc)
      pa[kc] = *(const short8*)(ps + fr * 64 + (((kc * 4 + hi) ^ (fr & 7)) << 3));

    // O += P V   (swizzled V^T reads)
    __builtin_amdgcn_s_setprio(1);
#pragma unroll
    for (int kc = 0; kc < 2; ++kc)
#pragma unroll
      for (int n = 0; n < 8; ++n) {
        const int row = n * 16 + fr;
        short8 b = *(const short8*)(&Vs[buf][row * 64 + (((kc * 4 + hi) ^ (fr & 7)) << 3)]);
        oacc[n] = __builtin_amdgcn_mfma_f32_16x16x32_bf16(pa[kc], b, oacc[n], 0, 0, 0);
      }
    __builtin_amdgcn_s_setprio(0);
    __syncthreads();
  }

  // deferred row-sum reduce, normalize + store [S][H*DH]
  float rl[4];
#pragma unroll
  for (int r = 0; r < 4; ++r) {
    float v = lsum[r];
    v += __shfl_xor(v, 1); v += __shfl_xor(v, 2);
    v += __shfl_xor(v, 4); v += __shfl_xor(v, 8);
    rl[r] = 1.0f / v;
  }
#pragma unroll
  for (int n = 0; n < 8; ++n)
#pragma unroll
    for (int r = 0; r < 4; ++r) {
      const float v = oacc[n][r] * rl[r];
      ao[(size_t)(q0 + fq4 + r) * DD + h * DHD + n * 16 + fr] = f2bf(v);
    }
}

// ---------------- launch ----------------
extern "C" void kernel_launch(void* const* d_in, const int* in_sizes, int n_in,
                              void* d_out, int out_size, void* d_ws, size_t ws_size,
                              hipStream_t stream) {
  const float* x        = (const float*)d_in[0];
  const float* rope_cos = (const float*)d_in[1];
  const float* rope_sin = (const float*)d_in[2];
  // d_in[3] = mask: deterministic causal, handled inline
  const float* wq = (const float*)d_in[4];
  const float* wk = (const float*)d_in[5];
  const float* wv = (const float*)d_in[6];
  const float* wo = (const float*)d_in[7];
  float* out = (float*)d_out;

  // Workspace: 8 x 8MB = 64MB. ao aliases wqb (dead after gemm_qkv).
  u16* ws = (u16*)d_ws;
  const size_t SZ = (size_t)SS * DD;
  u16* xb  = ws + 0 * SZ;
  u16* wqb = ws + 1 * SZ;
  u16* wkb = ws + 2 * SZ;
  u16* wvb = ws + 3 * SZ;
  u16* wob = ws + 4 * SZ;
  u16* qt  = ws + 5 * SZ;
  u16* kt  = ws + 6 * SZ;
  u16* vt  = ws + 7 * SZ;
  u16* ao  = wqb;

  cvt5<<<dim3((int)(SZ / (256 * 8)), 5), 256, 0, stream>>>(
      x, wq, wk, wv, wo, xb, wqb, wkb, wvb, wob);

  gemm_qkv<<<dim3(16, 16, 3), 256, 0, stream>>>(
      xb, wqb, wkb, wvb, rope_cos, rope_sin, qt, kt, vt);

  attn_fwd<<<512, 256, 0, stream>>>(qt, kt, vt, ao);

  gemm_bt<<<dim3(16, 16), 256, 0, stream>>>(ao, wob, out);
}

// Round 10
// 298.297 us; speedup vs baseline: 1.0895x; 1.0895x over previous
//
#include <hip/hip_runtime.h>

// Problem constants (B=1)
#define SS 2048
#define DD 2048
#define HH 16
#define DHD 128

// scores scale: reference divides by sqrt(DH) with DH=128
#define SCORE_SCALE 0.08838834764831845f
// p = exp(50*tanh(u)-50) with u = s*SCORE_SCALE/50  ==>  p = exp(-100/(1+e^{2u}))
#define C2 0.0035355339059327377f

typedef unsigned short u16;
typedef __attribute__((ext_vector_type(8))) short short8;
typedef __attribute__((ext_vector_type(4))) short short4v;
typedef __attribute__((ext_vector_type(4))) float f32x4;

__device__ __forceinline__ float bf2f(u16 v) {
  union { unsigned u; float f; } x; x.u = ((unsigned)v) << 16; return x.f;
}
__device__ __forceinline__ u16 f2bf(float f) {
  union { float f; unsigned u; } x; x.f = f;
  unsigned r = (x.u + 0x7fffu + ((x.u >> 16) & 1u)) >> 16;  // RTNE
  return (u16)r;
}

// async global->LDS, 16B per lane; LDS dest = wave-uniform base + lane*16
#define GL2LDS16(g, l) __builtin_amdgcn_global_load_lds( \
    (const __attribute__((address_space(1))) void*)(g),   \
    (__attribute__((address_space(3))) void*)(l), 16, 0, 0)

// ---------------- batched f32 -> bf16 convert (5 tensors in one launch) ------
__global__ __launch_bounds__(256) void cvt5(const float* __restrict__ i0,
                                            const float* __restrict__ i1,
                                            const float* __restrict__ i2,
                                            const float* __restrict__ i3,
                                            const float* __restrict__ i4,
                                            u16* __restrict__ o0, u16* __restrict__ o1,
                                            u16* __restrict__ o2, u16* __restrict__ o3,
                                            u16* __restrict__ o4) {
  const int z = blockIdx.y;
  const float* in = (z == 0) ? i0 : (z == 1) ? i1 : (z == 2) ? i2 : (z == 3) ? i3 : i4;
  u16* out = (z == 0) ? o0 : (z == 1) ? o1 : (z == 2) ? o2 : (z == 3) ? o3 : o4;
  int i = (blockIdx.x * 256 + threadIdx.x) * 8;
  float4 a = *(const float4*)(in + i);
  float4 b = *(const float4*)(in + i + 4);
  short8 o;
  o[0] = (short)f2bf(a.x); o[1] = (short)f2bf(a.y);
  o[2] = (short)f2bf(a.z); o[3] = (short)f2bf(a.w);
  o[4] = (short)f2bf(b.x); o[5] = (short)f2bf(b.y);
  o[6] = (short)f2bf(b.z); o[7] = (short)f2bf(b.w);
  *(short8*)(out + i) = o;
}

// ============ shared GEMM K-loop pieces (128x128 tile, BK=32, 2-phase) =======
// LDS swizzle: element (row, 8-elem chunk c) stored at slot c ^ ((row>>1)&3).
// Rows 0..7 cover 8 distinct 16B segments = all 32 banks; rows 8..15 repeat
// -> 2 lanes/bank = free. VERIFIED round 9: SQ_LDS_BANK_CONFLICT = 0.
// Staging keeps LDS dest LINEAR (gl2lds req) and pre-swizzles the GLOBAL
// source chunk (m173 pattern).

#define GEMM_STAGE(Asrc, Bsrc, Adst, Bdst, kofs)                               \
  _Pragma("unroll")                                                            \
  for (int half = 0; half < 2; ++half) {                                       \
    const int rb = half * 64 + wave * 16;                                      \
    GL2LDS16(Asrc + (size_t)(bm + rb + lrow) * DD + (kofs) + c8s, Adst + rb * 32); \
    GL2LDS16(Bsrc + (size_t)(bn + rb + lrow) * DD + (kofs) + c8s, Bdst + rb * 32); \
  }

#define GEMM_COMPUTE(Abuf, Bbuf)                                               \
  {                                                                            \
    short8 af[4], bb[4];                                                       \
    _Pragma("unroll")                                                          \
    for (int m = 0; m < 4; ++m) {                                              \
      const int row = wm + m * 16 + fr;                                        \
      af[m] = *(const short8*)(Abuf + row * 32 + (hi ^ ((row >> 1) & 3)) * 8); \
    }                                                                          \
    _Pragma("unroll")                                                          \
    for (int n = 0; n < 4; ++n) {                                              \
      const int row = wn + n * 16 + fr;                                        \
      bb[n] = *(const short8*)(Bbuf + row * 32 + (hi ^ ((row >> 1) & 3)) * 8); \
    }                                                                          \
    __builtin_amdgcn_s_setprio(1);                                             \
    _Pragma("unroll")                                                          \
    for (int m = 0; m < 4; ++m)                                                \
      _Pragma("unroll")                                                        \
      for (int n = 0; n < 4; ++n)                                              \
        acc[m][n] = __builtin_amdgcn_mfma_f32_16x16x32_bf16(af[m], bb[n], acc[m][n], 0, 0, 0); \
    __builtin_amdgcn_s_setprio(0);                                             \
  }

// 2-phase double-buffered K-loop over DD, named buffers (rule #20)
#define GEMM_KLOOP(A_, B_)                                                     \
  GEMM_STAGE(A_, B_, As0, Bs0, 0)                                              \
  __syncthreads();                                                             \
  for (int kk = 0; kk < DD / 32; kk += 2) {                                    \
    if (kk + 1 < DD / 32) { GEMM_STAGE(A_, B_, As1, Bs1, (kk + 1) * 32) }      \
    GEMM_COMPUTE(As0, Bs0)                                                     \
    __syncthreads();                                                           \
    if (kk + 2 < DD / 32) { GEMM_STAGE(A_, B_, As0, Bs0, (kk + 2) * 32) }      \
    GEMM_COMPUTE(As1, Bs1)                                                     \
    __syncthreads();                                                           \
  }

// ---------------- out-proj GEMM: C[M][N] = A[M][K] * B[N][K]^T, f32 out ------
__global__ __launch_bounds__(256) void gemm_bt(const u16* __restrict__ A,
                                               const u16* __restrict__ B,
                                               float* __restrict__ C) {
  __shared__ u16 smem[16384];  // As0|As1|Bs0|Bs1 (4KB elems each)
  u16* As0 = smem;            u16* As1 = smem + 4096;
  u16* Bs0 = smem + 8192;     u16* Bs1 = smem + 12288;
  const int tid = threadIdx.x, wave = tid >> 6, lane = tid & 63;
  const int wm = (wave >> 1) * 64, wn = (wave & 1) * 64;
  const int bm = blockIdx.y * 128, bn = blockIdx.x * 128;
  const int lrow = lane >> 2;
  const int c8s = ((lane & 3) ^ ((lrow >> 1) & 3)) * 8;  // pre-swizzled src chunk
  const int fr = lane & 15, hi = lane >> 4, fq4 = hi * 4;
  f32x4 acc[4][4] = {};
  GEMM_KLOOP(A, B)
#pragma unroll
  for (int m = 0; m < 4; ++m)
#pragma unroll
    for (int n = 0; n < 4; ++n) {
      const int row0 = bm + wm + m * 16 + fq4;
      const int col  = bn + wn + n * 16 + fr;
#pragma unroll
      for (int r = 0; r < 4; ++r)
        C[(size_t)(row0 + r) * DD + col] = acc[m][n][r];
    }
}

// ---------------- z-batched QKV GEMM (z=0:Q, 1:K, 2:V-transposed) ------------
// Round-5 structure (measured 70us w/ conflicts; now conflict-free).
// No RoPE fusion: round-9 showed it bloats VGPR 72->144 (occupancy 28->11%)
// and re-fetches 64MB of f32 tables past L2. Separate rope2 kernel instead.
__global__ __launch_bounds__(256) void gemm_qkv(const u16* __restrict__ A,
                                                const u16* __restrict__ Bq,
                                                const u16* __restrict__ Bk,
                                                const u16* __restrict__ Bv,
                                                u16* __restrict__ Cq,
                                                u16* __restrict__ Ck,
                                                u16* __restrict__ Cvt) {
  __shared__ u16 smem[16384];
  u16* As0 = smem;            u16* As1 = smem + 4096;
  u16* Bs0 = smem + 8192;     u16* Bs1 = smem + 12288;
  const int z = blockIdx.z;
  const u16* B = (z == 0) ? Bq : (z == 1) ? Bk : Bv;
  const int tid = threadIdx.x, wave = tid >> 6, lane = tid & 63;
  const int wm = (wave >> 1) * 64, wn = (wave & 1) * 64;
  const int bm = blockIdx.y * 128, bn = blockIdx.x * 128;
  const int lrow = lane >> 2;
  const int c8s = ((lane & 3) ^ ((lrow >> 1) & 3)) * 8;
  const int fr = lane & 15, hi = lane >> 4, fq4 = hi * 4;
  f32x4 acc[4][4] = {};
  GEMM_KLOOP(A, B)
  u16* Cn = (z == 0) ? Cq : Ck;
#pragma unroll
  for (int m = 0; m < 4; ++m)
#pragma unroll
    for (int n = 0; n < 4; ++n) {
      const int row0 = bm + wm + m * 16 + fq4;
      const int col  = bn + wn + n * 16 + fr;
      if (z < 2) {
#pragma unroll
        for (int r = 0; r < 4; ++r)
          Cn[(size_t)(row0 + r) * DD + col] = f2bf(acc[m][n][r]);
      } else {
        short4v t;
#pragma unroll
        for (int r = 0; r < 4; ++r) t[r] = (short)f2bf(acc[m][n][r]);
        *(short4v*)(Cvt + (size_t)col * SS + row0) = t;
      }
    }
}

// ---------------- RoPE: q/k [S][H*DH] -> [H][S][DH], vectorized x8 ----------
// One thread = 8 contiguous d-elems of one (s,h); partner elems at e^64.
// Q and K in one pass (cos/sin loaded once). Tables are 2MB -> L2-resident.
__global__ __launch_bounds__(256) void rope2(const u16* __restrict__ qin,
                                             const u16* __restrict__ kin,
                                             const float* __restrict__ cosd,
                                             const float* __restrict__ sind,
                                             u16* __restrict__ qt,
                                             u16* __restrict__ kt) {
  const int e = (blockIdx.x * 256 + threadIdx.x) * 8;  // index into [S][H*DH]
  const int s = e >> 11, col = e & 2047;
  const int h = col >> 7, d = col & 127;
  const float sgn = (d & 64) ? 1.0f : -1.0f;  // rotate_half sign
  short8 qa = *(const short8*)(qin + e);
  short8 qp = *(const short8*)(qin + (e ^ 64));
  short8 ka = *(const short8*)(kin + e);
  short8 kp = *(const short8*)(kin + (e ^ 64));
  f32x4 c0 = *(const f32x4*)(cosd + s * DHD + d);
  f32x4 c1 = *(const f32x4*)(cosd + s * DHD + d + 4);
  f32x4 s0 = *(const f32x4*)(sind + s * DHD + d);
  f32x4 s1 = *(const f32x4*)(sind + s * DHD + d + 4);
  short8 oq, ok;
#pragma unroll
  for (int j = 0; j < 8; ++j) {
    const float c = (j < 4) ? c0[j] : c1[j - 4];
    const float sn = (j < 4) ? s0[j] : s1[j - 4];
    oq[j] = (short)f2bf(bf2f((u16)qa[j]) * c + sgn * bf2f((u16)qp[j]) * sn);
    ok[j] = (short)f2bf(bf2f((u16)ka[j]) * c + sgn * bf2f((u16)kp[j]) * sn);
  }
  const size_t o = ((size_t)h * SS + s) * DHD + d;
  *(short8*)(qt + o) = oq;
  *(short8*)(kt + o) = ok;
}

// ---------------- Flash attention (causal, tanh soft-cap 50) -----------------
// 1-D grid 512 blocks. h = (bid&7)+8*((bid>>3)&1): each XCD keeps 2 heads' K/V
// in its L2. qb = 31-(bid>>4): LPT schedule. FIXED-max softmax (cap -> m=50):
//   p = exp(s-50) = exp(-100/(1+e^{2u})) -- no online max/rescale.
__global__ __launch_bounds__(256) void attn_fwd(const u16* __restrict__ qt,
                                                const u16* __restrict__ kt,
                                                const u16* __restrict__ vt,
                                                u16* __restrict__ ao) {
  __shared__ u16 Ks[2][64 * 128];
  __shared__ u16 Vs[2][128 * 64];
  __shared__ u16 Ps[4][16 * 64];
  const int bid = blockIdx.x;
  const int h  = (bid & 7) + 8 * ((bid >> 3) & 1);
  const int qb = (SS / 64 - 1) - (bid >> 4);
  const int tid = threadIdx.x, wave = tid >> 6, lane = tid & 63;
  const int q0 = qb * 64 + wave * 16;
  const int fr = lane & 15, hi = lane >> 4, fq8 = hi * 8, fq4 = hi * 4;

  const int kbrow0 = wave * 4 + (lane >> 4);
  const int kc8    = (lane & 15);
  const int vbrow0 = wave * 8 + (lane >> 3);
  const int vk8    = (lane & 7) ^ ((lane >> 3) & 7);

  short8 qf[4];
#pragma unroll
  for (int c = 0; c < 4; ++c)
    qf[c] = *(const short8*)(qt + ((size_t)h * SS + q0 + fr) * DHD + c * 32 + fq8);

  f32x4 oacc[8] = {};
  float lsum[4] = {0.f, 0.f, 0.f, 0.f};

  const int nt = qb + 1;

  auto STAGE = [&](int t, int buf) {
    const int kb = t * 64;
#pragma unroll
    for (int i = 0; i < 4; ++i) {
      const int krow = i * 16 + kbrow0;
      const int c8 = kc8 ^ (krow & 7);
      GL2LDS16(kt + ((size_t)h * SS + kb + krow) * DHD + c8 * 8,
               &Ks[buf][(i * 16 + wave * 4) * 128]);
    }
#pragma unroll
    for (int i = 0; i < 4; ++i) {
      const int vrow = i * 32 + vbrow0;
      GL2LDS16(vt + ((size_t)h * DHD + vrow) * SS + kb + vk8 * 8,
               &Vs[buf][(i * 32 + wave * 8) * 64]);
    }
  };

  STAGE(0, 0);
  __syncthreads();

  for (int t = 0; t < nt; ++t) {
    const int buf = t & 1;
    if (t + 1 < nt) STAGE(t + 1, buf ^ 1);
    const int kb = t * 64;

    // S = Q K^T  (swizzled K reads)
    f32x4 sacc[4] = {};
    __builtin_amdgcn_s_setprio(1);
#pragma unroll
    for (int n = 0; n < 4; ++n) {
      const int row = n * 16 + fr;
#pragma unroll
      for (int c = 0; c < 4; ++c) {
        short8 b = *(const short8*)(&Ks[buf][row * 128 + ((c * 4 + hi) ^ (fr & 7)) * 8]);
        sacc[n] = __builtin_amdgcn_mfma_f32_16x16x32_bf16(qf[c], b, sacc[n], 0, 0, 0);
      }
    }
    __builtin_amdgcn_s_setprio(0);

    // fixed-max softcap softmax: p = exp(-100/(1+e^{2u})), masked -> 0
    const bool diag = (t == nt - 1);
    float p[4][4];
#pragma unroll
    for (int n = 0; n < 4; ++n)
#pragma unroll
      for (int r = 0; r < 4; ++r) {
        const float w = __expf(sacc[n][r] * C2);
        float pv = __expf(-100.0f * __builtin_amdgcn_rcpf(1.0f + w));
        if (diag) {
          const int kg = kb + n * 16 + fr;
          if (kg > q0 + fq4 + r) pv = 0.0f;
        }
        p[n][r] = pv;
        lsum[r] += pv;
      }

    // P (C-layout) -> per-wave LDS (swizzled) -> A-fragment layout
    u16* ps = &Ps[wave][0];
#pragma unroll
    for (int n = 0; n < 4; ++n)
#pragma unroll
      for (int r = 0; r < 4; ++r) {
        const int prow = fq4 + r;
        const int chunk = n * 2 + (fr >> 3);
        ps[prow * 64 + ((chunk ^ (prow & 7)) << 3) + (fr & 7)] = f2bf(p[n][r]);
      }
    short8 pa[2];
#pragma unroll
    for (int kc = 0; kc < 2; ++kc)
      pa[kc] = *(const short8*)(ps + fr * 64 + (((kc * 4 + hi) ^ (fr & 7)) << 3));

    // O += P V   (swizzled V^T reads)
    __builtin_amdgcn_s_setprio(1);
#pragma unroll
    for (int kc = 0; kc < 2; ++kc)
#pragma unroll
      for (int n = 0; n < 8; ++n) {
        const int row = n * 16 + fr;
        short8 b = *(const short8*)(&Vs[buf][row * 64 + (((kc * 4 + hi) ^ (fr & 7)) << 3)]);
        oacc[n] = __builtin_amdgcn_mfma_f32_16x16x32_bf16(pa[kc], b, oacc[n], 0, 0, 0);
      }
    __builtin_amdgcn_s_setprio(0);
    __syncthreads();
  }

  // deferred row-sum reduce, normalize + store [S][H*DH]
  float rl[4];
#pragma unroll
  for (int r = 0; r < 4; ++r) {
    float v = lsum[r];
    v += __shfl_xor(v, 1); v += __shfl_xor(v, 2);
    v += __shfl_xor(v, 4); v += __shfl_xor(v, 8);
    rl[r] = 1.0f / v;
  }
#pragma unroll
  for (int n = 0; n < 8; ++n)
#pragma unroll
    for (int r = 0; r < 4; ++r) {
      const float v = oacc[n][r] * rl[r];
      ao[(size_t)(q0 + fq4 + r) * DD + h * DHD + n * 16 + fr] = f2bf(v);
    }
}

// ---------------- launch ----------------
extern "C" void kernel_launch(void* const* d_in, const int* in_sizes, int n_in,
                              void* d_out, int out_size, void* d_ws, size_t ws_size,
                              hipStream_t stream) {
  const float* x        = (const float*)d_in[0];
  const float* rope_cos = (const float*)d_in[1];
  const float* rope_sin = (const float*)d_in[2];
  // d_in[3] = mask: deterministic causal, handled inline
  const float* wq = (const float*)d_in[4];
  const float* wk = (const float*)d_in[5];
  const float* wv = (const float*)d_in[6];
  const float* wo = (const float*)d_in[7];
  float* out = (float*)d_out;

  // Workspace: 8 x 8MB = 64MB. qt aliases wqb, kt aliases wkb, ao aliases wvb
  // (weights dead after gemm_qkv; sequential stream makes reuse safe).
  u16* ws = (u16*)d_ws;
  const size_t SZ = (size_t)SS * DD;
  u16* xb  = ws + 0 * SZ;
  u16* wqb = ws + 1 * SZ;
  u16* wkb = ws + 2 * SZ;
  u16* wvb = ws + 3 * SZ;
  u16* wob = ws + 4 * SZ;
  u16* q_  = ws + 5 * SZ;
  u16* k_  = ws + 6 * SZ;
  u16* vt  = ws + 7 * SZ;
  u16* qt  = wqb;
  u16* kt  = wkb;
  u16* ao  = wvb;

  cvt5<<<dim3((int)(SZ / (256 * 8)), 5), 256, 0, stream>>>(
      x, wq, wk, wv, wo, xb, wqb, wkb, wvb, wob);

  gemm_qkv<<<dim3(16, 16, 3), 256, 0, stream>>>(
      xb, wqb, wkb, wvb, q_, k_, vt);

  rope2<<<(int)(SZ / (256 * 8)), 256, 0, stream>>>(
      q_, k_, rope_cos, rope_sin, qt, kt);

  attn_fwd<<<512, 256, 0, stream>>>(qt, kt, vt, ao);

  gemm_bt<<<dim3(16, 16), 256, 0, stream>>>(ao, wob, out);
}

// Round 12
// 281.875 us; speedup vs baseline: 1.1530x; 1.0583x over previous
//
#include <hip/hip_runtime.h>

// Problem constants (B=1)
#define SS 2048
#define DD 2048
#define HH 16
#define DHD 128

// scores scale: reference divides by sqrt(DH) with DH=128
#define SCORE_SCALE 0.08838834764831845f
// p = exp(50*tanh(u)-50) with u = s*SCORE_SCALE/50  ==>  p = exp(-100/(1+e^{2u}))
#define C2 0.0035355339059327377f

typedef unsigned short u16;
typedef __attribute__((ext_vector_type(8))) short short8;
typedef __attribute__((ext_vector_type(4))) short short4v;
typedef __attribute__((ext_vector_type(4))) float f32x4;

__device__ __forceinline__ float bf2f(u16 v) {
  union { unsigned u; float f; } x; x.u = ((unsigned)v) << 16; return x.f;
}
__device__ __forceinline__ u16 f2bf(float f) {
  union { float f; unsigned u; } x; x.f = f;
  unsigned r = (x.u + 0x7fffu + ((x.u >> 16) & 1u)) >> 16;  // RTNE
  return (u16)r;
}

// async global->LDS, 16B per lane; LDS dest = wave-uniform base + lane*16
#define GL2LDS16(g, l) __builtin_amdgcn_global_load_lds( \
    (const __attribute__((address_space(1))) void*)(g),   \
    (__attribute__((address_space(3))) void*)(l), 16, 0, 0)

// ---------------- batched f32 -> bf16 convert (5 tensors in one launch) ------
__global__ __launch_bounds__(256) void cvt5(const float* __restrict__ i0,
                                            const float* __restrict__ i1,
                                            const float* __restrict__ i2,
                                            const float* __restrict__ i3,
                                            const float* __restrict__ i4,
                                            u16* __restrict__ o0, u16* __restrict__ o1,
                                            u16* __restrict__ o2, u16* __restrict__ o3,
                                            u16* __restrict__ o4) {
  const int z = blockIdx.y;
  const float* in = (z == 0) ? i0 : (z == 1) ? i1 : (z == 2) ? i2 : (z == 3) ? i3 : i4;
  u16* out = (z == 0) ? o0 : (z == 1) ? o1 : (z == 2) ? o2 : (z == 3) ? o3 : o4;
  int i = (blockIdx.x * 256 + threadIdx.x) * 8;
  float4 a = *(const float4*)(in + i);
  float4 b = *(const float4*)(in + i + 4);
  short8 o;
  o[0] = (short)f2bf(a.x); o[1] = (short)f2bf(a.y);
  o[2] = (short)f2bf(a.z); o[3] = (short)f2bf(a.w);
  o[4] = (short)f2bf(b.x); o[5] = (short)f2bf(b.y);
  o[6] = (short)f2bf(b.z); o[7] = (short)f2bf(b.w);
  *(short8*)(out + i) = o;
}

// ============ shared GEMM K-loop pieces (128x128 tile, BK=32, 2-phase) =======
// LDS swizzle: element (row, 8-elem chunk c) stored at slot c ^ ((row>>1)&3).
// VERIFIED round 9/10: SQ_LDS_BANK_CONFLICT = 0. Staging keeps LDS dest
// LINEAR (gl2lds req) and pre-swizzles the GLOBAL source chunk (m173).

#define GEMM_STAGE(Asrc, Bsrc, Adst, Bdst, kofs)                               \
  _Pragma("unroll")                                                            \
  for (int half = 0; half < 2; ++half) {                                       \
    const int rb = half * 64 + wave * 16;                                      \
    GL2LDS16(Asrc + (size_t)(bm + rb + lrow) * DD + (kofs) + c8s, Adst + rb * 32); \
    GL2LDS16(Bsrc + (size_t)(bn + rb + lrow) * DD + (kofs) + c8s, Bdst + rb * 32); \
  }

#define GEMM_COMPUTE(Abuf, Bbuf)                                               \
  {                                                                            \
    short8 af[4], bb[4];                                                       \
    _Pragma("unroll")                                                          \
    for (int m = 0; m < 4; ++m) {                                              \
      const int row = wm + m * 16 + fr;                                        \
      af[m] = *(const short8*)(Abuf + row * 32 + (hi ^ ((row >> 1) & 3)) * 8); \
    }                                                                          \
    _Pragma("unroll")                                                          \
    for (int n = 0; n < 4; ++n) {                                              \
      const int row = wn + n * 16 + fr;                                        \
      bb[n] = *(const short8*)(Bbuf + row * 32 + (hi ^ ((row >> 1) & 3)) * 8); \
    }                                                                          \
    __builtin_amdgcn_s_setprio(1);                                             \
    _Pragma("unroll")                                                          \
    for (int m = 0; m < 4; ++m)                                                \
      _Pragma("unroll")                                                        \
      for (int n = 0; n < 4; ++n)                                              \
        acc[m][n] = __builtin_amdgcn_mfma_f32_16x16x32_bf16(af[m], bb[n], acc[m][n], 0, 0, 0); \
    __builtin_amdgcn_s_setprio(0);                                             \
  }

// 2-phase double-buffered K-loop over DD, named buffers (rule #20)
#define GEMM_KLOOP(A_, B_)                                                     \
  GEMM_STAGE(A_, B_, As0, Bs0, 0)                                              \
  __syncthreads();                                                             \
  for (int kk = 0; kk < DD / 32; kk += 2) {                                    \
    if (kk + 1 < DD / 32) { GEMM_STAGE(A_, B_, As1, Bs1, (kk + 1) * 32) }      \
    GEMM_COMPUTE(As0, Bs0)                                                     \
    __syncthreads();                                                           \
    if (kk + 2 < DD / 32) { GEMM_STAGE(A_, B_, As0, Bs0, (kk + 2) * 32) }      \
    GEMM_COMPUTE(As1, Bs1)                                                     \
    __syncthreads();                                                           \
  }

// ------ out-proj GEMM, in-block split-K=2: C[M][N] = A*B^T, f32 out ---------
// 512 threads = 8 waves. Waves 0-3: K[0,1024) pipeline; waves 4-7: K[1024,2048)
// in a SEPARATE 32KB LDS staging region (barriers stay block-uniform: both
// groups run identical 16-iteration loops). Epilogue: group 1 dumps f32
// partials to LDS [128][132] (pad->2-way banks), group 0 adds + stores.
// Rationale (r10 counters): 256 blocks @ 4 waves/CU was the worst-fill GEMM;
// this doubles resident waves/CU without extra HBM traffic or kernels.
__global__ __launch_bounds__(512) void gemm_bt_sk(const u16* __restrict__ A,
                                                  const u16* __restrict__ B,
                                                  float* __restrict__ C) {
  __shared__ u16 smem[33792];  // 67.5KB: 2x32KB staging, reused as f32 red[128][132]
  const int tid = threadIdx.x;
  const int wave8 = tid >> 6, lane = tid & 63;
  const int gq = wave8 >> 2;         // K-group
  const int wave = wave8 & 3;        // within-group wave (quadrant + staging)
  const int wm = (wave >> 1) * 64, wn = (wave & 1) * 64;
  const int bm = blockIdx.y * 128, bn = blockIdx.x * 128;
  const int lrow = lane >> 2;
  const int c8s = ((lane & 3) ^ ((lrow >> 1) & 3)) * 8;
  const int fr = lane & 15, hi = lane >> 4, fq4 = hi * 4;
  u16* base = smem + gq * 16384;
  u16* As0 = base;            u16* As1 = base + 4096;
  u16* Bs0 = base + 8192;     u16* Bs1 = base + 12288;
  const int k0 = gq * 1024;
  f32x4 acc[4][4] = {};
  GEMM_STAGE(A, B, As0, Bs0, k0)
  __syncthreads();
  for (int kk = 0; kk < 32; kk += 2) {
    if (kk + 1 < 32) { GEMM_STAGE(A, B, As1, Bs1, k0 + (kk + 1) * 32) }
    GEMM_COMPUTE(As0, Bs0)
    __syncthreads();
    if (kk + 2 < 32) { GEMM_STAGE(A, B, As0, Bs0, k0 + (kk + 2) * 32) }
    GEMM_COMPUTE(As1, Bs1)
    __syncthreads();
  }
  // cross-group reduce via LDS (group 1 -> group 0)
  float* red = (float*)smem;
  if (gq == 1) {
#pragma unroll
    for (int m = 0; m < 4; ++m)
#pragma unroll
      for (int n = 0; n < 4; ++n) {
        const int lr0 = wm + m * 16 + fq4;
        const int lc  = wn + n * 16 + fr;
#pragma unroll
        for (int r = 0; r < 4; ++r)
          red[(lr0 + r) * 132 + lc] = acc[m][n][r];
      }
  }
  __syncthreads();
  if (gq == 0) {
#pragma unroll
    for (int m = 0; m < 4; ++m)
#pragma unroll
      for (int n = 0; n < 4; ++n) {
        const int row0 = bm + wm + m * 16 + fq4;
        const int col  = bn + wn + n * 16 + fr;
        const int lr0 = wm + m * 16 + fq4;
        const int lc  = wn + n * 16 + fr;
#pragma unroll
        for (int r = 0; r < 4; ++r)
          C[(size_t)(row0 + r) * DD + col] = acc[m][n][r] + red[(lr0 + r) * 132 + lc];
      }
  }
}

// ---------------- z-batched QKV GEMM (z=0:Q, 1:K, 2:V-transposed) ------------
// Measured r10: 64.8us, 795 TF effective, conflicts 0, occupancy 28%.
__global__ __launch_bounds__(256) void gemm_qkv(const u16* __restrict__ A,
                                                const u16* __restrict__ Bq,
                                                const u16* __restrict__ Bk,
                                                const u16* __restrict__ Bv,
                                                u16* __restrict__ Cq,
                                                u16* __restrict__ Ck,
                                                u16* __restrict__ Cvt) {
  __shared__ u16 smem[16384];
  u16* As0 = smem;            u16* As1 = smem + 4096;
  u16* Bs0 = smem + 8192;     u16* Bs1 = smem + 12288;
  const int z = blockIdx.z;
  const u16* B = (z == 0) ? Bq : (z == 1) ? Bk : Bv;
  const int tid = threadIdx.x, wave = tid >> 6, lane = tid & 63;
  const int wm = (wave >> 1) * 64, wn = (wave & 1) * 64;
  const int bm = blockIdx.y * 128, bn = blockIdx.x * 128;
  const int lrow = lane >> 2;
  const int c8s = ((lane & 3) ^ ((lrow >> 1) & 3)) * 8;
  const int fr = lane & 15, hi = lane >> 4, fq4 = hi * 4;
  f32x4 acc[4][4] = {};
  GEMM_KLOOP(A, B)
  u16* Cn = (z == 0) ? Cq : Ck;
#pragma unroll
  for (int m = 0; m < 4; ++m)
#pragma unroll
    for (int n = 0; n < 4; ++n) {
      const int row0 = bm + wm + m * 16 + fq4;
      const int col  = bn + wn + n * 16 + fr;
      if (z < 2) {
#pragma unroll
        for (int r = 0; r < 4; ++r)
          Cn[(size_t)(row0 + r) * DD + col] = f2bf(acc[m][n][r]);
      } else {
        short4v t;
#pragma unroll
        for (int r = 0; r < 4; ++r) t[r] = (short)f2bf(acc[m][n][r]);
        *(short4v*)(Cvt + (size_t)col * SS + row0) = t;
      }
    }
}

// ---------------- RoPE: q/k [S][H*DH] -> [H][S][DH], vectorized x8 ----------
__global__ __launch_bounds__(256) void rope2(const u16* __restrict__ qin,
                                             const u16* __restrict__ kin,
                                             const float* __restrict__ cosd,
                                             const float* __restrict__ sind,
                                             u16* __restrict__ qt,
                                             u16* __restrict__ kt) {
  const int e = (blockIdx.x * 256 + threadIdx.x) * 8;  // index into [S][H*DH]
  const int s = e >> 11, col = e & 2047;
  const int h = col >> 7, d = col & 127;
  const float sgn = (d & 64) ? 1.0f : -1.0f;  // rotate_half sign
  short8 qa = *(const short8*)(qin + e);
  short8 qp = *(const short8*)(qin + (e ^ 64));
  short8 ka = *(const short8*)(kin + e);
  short8 kp = *(const short8*)(kin + (e ^ 64));
  f32x4 c0 = *(const f32x4*)(cosd + s * DHD + d);
  f32x4 c1 = *(const f32x4*)(cosd + s * DHD + d + 4);
  f32x4 s0 = *(const f32x4*)(sind + s * DHD + d);
  f32x4 s1 = *(const f32x4*)(sind + s * DHD + d + 4);
  short8 oq, ok;
#pragma unroll
  for (int j = 0; j < 8; ++j) {
    const float c = (j < 4) ? c0[j] : c1[j - 4];
    const float sn = (j < 4) ? s0[j] : s1[j - 4];
    oq[j] = (short)f2bf(bf2f((u16)qa[j]) * c + sgn * bf2f((u16)qp[j]) * sn);
    ok[j] = (short)f2bf(bf2f((u16)ka[j]) * c + sgn * bf2f((u16)kp[j]) * sn);
  }
  const size_t o = ((size_t)h * SS + s) * DHD + d;
  *(short8*)(qt + o) = oq;
  *(short8*)(kt + o) = ok;
}

// ---------------- Flash attention (causal, tanh soft-cap 50) -----------------
// 1-D grid 512 blocks. h = (bid&7)+8*((bid>>3)&1): each XCD keeps 2 heads' K/V
// in its L2. qb = 31-(bid>>4): LPT schedule. FIXED-max softmax (cap -> m=50):
//   p = exp(s-50) = exp(-100/(1+e^{2u})) -- no online max/rescale.
__global__ __launch_bounds__(256) void attn_fwd(const u16* __restrict__ qt,
                                                const u16* __restrict__ kt,
                                                const u16* __restrict__ vt,
                                                u16* __restrict__ ao) {
  __shared__ u16 Ks[2][64 * 128];
  __shared__ u16 Vs[2][128 * 64];
  __shared__ u16 Ps[4][16 * 64];
  const int bid = blockIdx.x;
  const int h  = (bid & 7) + 8 * ((bid >> 3) & 1);
  const int qb = (SS / 64 - 1) - (bid >> 4);
  const int tid = threadIdx.x, wave = tid >> 6, lane = tid & 63;
  const int q0 = qb * 64 + wave * 16;
  const int fr = lane & 15, hi = lane >> 4, fq8 = hi * 8, fq4 = hi * 4;

  const int kbrow0 = wave * 4 + (lane >> 4);
  const int kc8    = (lane & 15);
  const int vbrow0 = wave * 8 + (lane >> 3);
  const int vk8    = (lane & 7) ^ ((lane >> 3) & 7);

  short8 qf[4];
#pragma unroll
  for (int c = 0; c < 4; ++c)
    qf[c] = *(const short8*)(qt + ((size_t)h * SS + q0 + fr) * DHD + c * 32 + fq8);

  f32x4 oacc[8] = {};
  float lsum[4] = {0.f, 0.f, 0.f, 0.f};

  const int nt = qb + 1;

  auto STAGE = [&](int t, int buf) {
    const int kb = t * 64;
#pragma unroll
    for (int i = 0; i < 4; ++i) {
      const int krow = i * 16 + kbrow0;
      const int c8 = kc8 ^ (krow & 7);
      GL2LDS16(kt + ((size_t)h * SS + kb + krow) * DHD + c8 * 8,
               &Ks[buf][(i * 16 + wave * 4) * 128]);
    }
#pragma unroll
    for (int i = 0; i < 4; ++i) {
      const int vrow = i * 32 + vbrow0;
      GL2LDS16(vt + ((size_t)h * DHD + vrow) * SS + kb + vk8 * 8,
               &Vs[buf][(i * 32 + wave * 8) * 64]);
    }
  };

  STAGE(0, 0);
  __syncthreads();

  for (int t = 0; t < nt; ++t) {
    const int buf = t & 1;
    if (t + 1 < nt) STAGE(t + 1, buf ^ 1);
    const int kb = t * 64;

    // S = Q K^T  (swizzled K reads)
    f32x4 sacc[4] = {};
    __builtin_amdgcn_s_setprio(1);
#pragma unroll
    for (int n = 0; n < 4; ++n) {
      const int row = n * 16 + fr;
#pragma unroll
      for (int c = 0; c < 4; ++c) {
        short8 b = *(const short8*)(&Ks[buf][row * 128 + ((c * 4 + hi) ^ (fr & 7)) * 8]);
        sacc[n] = __builtin_amdgcn_mfma_f32_16x16x32_bf16(qf[c], b, sacc[n], 0, 0, 0);
      }
    }
    __builtin_amdgcn_s_setprio(0);

    // fixed-max softcap softmax: p = exp(-100/(1+e^{2u})), masked -> 0
    const bool diag = (t == nt - 1);
    float p[4][4];
#pragma unroll
    for (int n = 0; n < 4; ++n)
#pragma unroll
      for (int r = 0; r < 4; ++r) {
        const float w = __expf(sacc[n][r] * C2);
        float pv = __expf(-100.0f * __builtin_amdgcn_rcpf(1.0f + w));
        if (diag) {
          const int kg = kb + n * 16 + fr;
          if (kg > q0 + fq4 + r) pv = 0.0f;
        }
        p[n][r] = pv;
        lsum[r] += pv;
      }

    // P (C-layout) -> per-wave LDS (swizzled) -> A-fragment layout
    u16* ps = &Ps[wave][0];
#pragma unroll
    for (int n = 0; n < 4; ++n)
#pragma unroll
      for (int r = 0; r < 4; ++r) {
        const int prow = fq4 + r;
        const int chunk = n * 2 + (fr >> 3);
        ps[prow * 64 + ((chunk ^ (prow & 7)) << 3) + (fr & 7)] = f2bf(p[n][r]);
      }
    short8 pa[2];
#pragma unroll
    for (int kc = 0; kc < 2; ++kc)
      pa[kc] = *(const short8*)(ps + fr * 64 + (((kc * 4 + hi) ^ (fr & 7)) << 3));

    // O += P V   (swizzled V^T reads)
    __builtin_amdgcn_s_setprio(1);
#pragma unroll
    for (int kc = 0; kc < 2; ++kc)
#pragma unroll
      for (int n = 0; n < 8; ++n) {
        const int row = n * 16 + fr;
        short8 b = *(const short8*)(&Vs[buf][row * 64 + (((kc * 4 + hi) ^ (fr & 7)) << 3)]);
        oacc[n] = __builtin_amdgcn_mfma_f32_16x16x32_bf16(pa[kc], b, oacc[n], 0, 0, 0);
      }
    __builtin_amdgcn_s_setprio(0);
    __syncthreads();
  }

  // deferred row-sum reduce, normalize + store [S][H*DH]
  float rl[4];
#pragma unroll
  for (int r = 0; r < 4; ++r) {
    float v = lsum[r];
    v += __shfl_xor(v, 1); v += __shfl_xor(v, 2);
    v += __shfl_xor(v, 4); v += __shfl_xor(v, 8);
    rl[r] = 1.0f / v;
  }
#pragma unroll
  for (int n = 0; n < 8; ++n)
#pragma unroll
    for (int r = 0; r < 4; ++r) {
      const float v = oacc[n][r] * rl[r];
      ao[(size_t)(q0 + fq4 + r) * DD + h * DHD + n * 16 + fr] = f2bf(v);
    }
}

// ---------------- launch ----------------
extern "C" void kernel_launch(void* const* d_in, const int* in_sizes, int n_in,
                              void* d_out, int out_size, void* d_ws, size_t ws_size,
                              hipStream_t stream) {
  const float* x        = (const float*)d_in[0];
  const float* rope_cos = (const float*)d_in[1];
  const float* rope_sin = (const float*)d_in[2];
  // d_in[3] = mask: deterministic causal, handled inline
  const float* wq = (const float*)d_in[4];
  const float* wk = (const float*)d_in[5];
  const float* wv = (const float*)d_in[6];
  const float* wo = (const float*)d_in[7];
  float* out = (float*)d_out;

  // Workspace: 8 x 8MB = 64MB. qt aliases wqb, kt aliases wkb, ao aliases wvb
  // (weights dead after gemm_qkv; sequential stream makes reuse safe).
  u16* ws = (u16*)d_ws;
  const size_t SZ = (size_t)SS * DD;
  u16* xb  = ws + 0 * SZ;
  u16* wqb = ws + 1 * SZ;
  u16* wkb = ws + 2 * SZ;
  u16* wvb = ws + 3 * SZ;
  u16* wob = ws + 4 * SZ;
  u16* q_  = ws + 5 * SZ;
  u16* k_  = ws + 6 * SZ;
  u16* vt  = ws + 7 * SZ;
  u16* qt  = wqb;
  u16* kt  = wkb;
  u16* ao  = wvb;

  cvt5<<<dim3((int)(SZ / (256 * 8)), 5), 256, 0, stream>>>(
      x, wq, wk, wv, wo, xb, wqb, wkb, wvb, wob);

  gemm_qkv<<<dim3(16, 16, 3), 256, 0, stream>>>(
      xb, wqb, wkb, wvb, q_, k_, vt);

  rope2<<<(int)(SZ / (256 * 8)), 256, 0, stream>>>(
      q_, k_, rope_cos, rope_sin, qt, kt);

  attn_fwd<<<512, 256, 0, stream>>>(qt, kt, vt, ao);

  gemm_bt_sk<<<dim3(16, 16), 512, 0, stream>>>(ao, wob, out);
}